// Round 11
// baseline (78.914 us; speedup 1.0000x reference)
//
#include <hip/hip_runtime.h>

#define S_DIM 4096
#define C_DIM 2048      // C1 == C2
#define N_DIM 1024
#define K_DIM 4096      // C1 + C2

// ---- split-K 256x256 GEMM ----
#define BM2 256
#define BN2 256
#define KS 4                    // K splits
#define KSL (K_DIM / KS)        // 1024 K per split
#define BK 32
#define NT2 (KSL / BK)          // 32 steps
#define TILE2 32768             // (256 A + 256 B rows) * 64 B
#define NBUF2 4                 // 128 KB LDS ring

// ---- fallback 128x128 (round-5, verified 46us) ----
#define BM1 128
#define BN1 128
#define NT1 (K_DIM / BK)        // 128
#define TILE1 16384
#define NBUF1 8

typedef __attribute__((ext_vector_type(8))) short bf16x8;
typedef __attribute__((ext_vector_type(8))) unsigned short u16x8;
typedef __attribute__((ext_vector_type(4))) float f32x4;

__device__ static inline unsigned short f2bf(float f) {
    unsigned int u = __float_as_uint(f);
    u += 0x7FFFu + ((u >> 16) & 1u);
    return (unsigned short)(u >> 16);
}
__device__ static inline float bf2f(unsigned short h) {
    return __uint_as_float((unsigned int)h << 16);
}

// ---------------- exp + cast to bf16 for A (both ll sources, one launch) ----------------
__global__ void exp_ll_kernel(const float* __restrict__ ll1,
                              const float* __restrict__ ll2,
                              unsigned short* __restrict__ A) {
    const int total4 = S_DIM * C_DIM / 4;
    int stride = gridDim.x * blockDim.x;
    for (int i = blockIdx.x * blockDim.x + threadIdx.x; i < total4; i += stride) {
        int e = i << 2;
        int r = e >> 11;          // src cols = 2048
        int c = e & 2047;
        size_t dst = ((size_t)r << 12) + c;
        float4 v = *reinterpret_cast<const float4*>(ll1 + e);
        ushort4 o;
        o.x = f2bf(__expf(v.x)); o.y = f2bf(__expf(v.y));
        o.z = f2bf(__expf(v.z)); o.w = f2bf(__expf(v.w));
        *reinterpret_cast<ushort4*>(A + dst) = o;
        float4 u = *reinterpret_cast<const float4*>(ll2 + e);
        ushort4 p;
        p.x = f2bf(__expf(u.x)); p.y = f2bf(__expf(u.y));
        p.z = f2bf(__expf(u.z)); p.w = f2bf(__expf(u.w));
        *reinterpret_cast<ushort4*>(A + dst + C_DIM) = p;
    }
}

// ---------------- w: exp->B (bf16) AND per-row logsumexp, fused ----------------
__global__ void w_kernel(const float* __restrict__ w1,
                         const float* __restrict__ w2,
                         unsigned short* __restrict__ B,
                         float* __restrict__ lz) {
    const int n = blockIdx.x;
    const int tid = threadIdx.x;          // 0..255
    const int lane = tid & 63, wv = tid >> 6;
    const float* r1 = w1 + ((size_t)n << 11);
    const float* r2 = w2 + ((size_t)n << 11);
    float4 v0 = *reinterpret_cast<const float4*>(r1 + tid * 8);
    float4 v1 = *reinterpret_cast<const float4*>(r1 + tid * 8 + 4);
    float4 u0 = *reinterpret_cast<const float4*>(r2 + tid * 8);
    float4 u1 = *reinterpret_cast<const float4*>(r2 + tid * 8 + 4);

    float mx = fmaxf(fmaxf(fmaxf(v0.x, v0.y), fmaxf(v0.z, v0.w)),
                     fmaxf(fmaxf(v1.x, v1.y), fmaxf(v1.z, v1.w)));
    mx = fmaxf(mx, fmaxf(fmaxf(fmaxf(u0.x, u0.y), fmaxf(u0.z, u0.w)),
                          fmaxf(fmaxf(u1.x, u1.y), fmaxf(u1.z, u1.w))));
    #pragma unroll
    for (int off = 32; off > 0; off >>= 1) mx = fmaxf(mx, __shfl_xor(mx, off));
    __shared__ float red[4];
    if (lane == 0) red[wv] = mx;
    __syncthreads();
    mx = fmaxf(fmaxf(red[0], red[1]), fmaxf(red[2], red[3]));

    float s = __expf(v0.x - mx) + __expf(v0.y - mx) + __expf(v0.z - mx) + __expf(v0.w - mx)
            + __expf(v1.x - mx) + __expf(v1.y - mx) + __expf(v1.z - mx) + __expf(v1.w - mx)
            + __expf(u0.x - mx) + __expf(u0.y - mx) + __expf(u0.z - mx) + __expf(u0.w - mx)
            + __expf(u1.x - mx) + __expf(u1.y - mx) + __expf(u1.z - mx) + __expf(u1.w - mx);
    #pragma unroll
    for (int off = 32; off > 0; off >>= 1) s += __shfl_xor(s, off);
    __shared__ float red2[4];
    if (lane == 0) red2[wv] = s;
    __syncthreads();
    if (tid == 0)
        lz[n] = mx + __logf(red2[0] + red2[1] + red2[2] + red2[3]);

    unsigned short* brow = B + ((size_t)n << 12);
    ushort4 o;
    o.x = f2bf(__expf(v0.x)); o.y = f2bf(__expf(v0.y));
    o.z = f2bf(__expf(v0.z)); o.w = f2bf(__expf(v0.w));
    *reinterpret_cast<ushort4*>(brow + tid * 8) = o;
    o.x = f2bf(__expf(v1.x)); o.y = f2bf(__expf(v1.y));
    o.z = f2bf(__expf(v1.z)); o.w = f2bf(__expf(v1.w));
    *reinterpret_cast<ushort4*>(brow + tid * 8 + 4) = o;
    o.x = f2bf(__expf(u0.x)); o.y = f2bf(__expf(u0.y));
    o.z = f2bf(__expf(u0.z)); o.w = f2bf(__expf(u0.w));
    *reinterpret_cast<ushort4*>(brow + C_DIM + tid * 8) = o;
    o.x = f2bf(__expf(u1.x)); o.y = f2bf(__expf(u1.y));
    o.z = f2bf(__expf(u1.z)); o.w = f2bf(__expf(u1.w));
    *reinterpret_cast<ushort4*>(brow + C_DIM + tid * 8 + 4) = o;
}

typedef const unsigned int __attribute__((address_space(1)))* gas_ptr;
typedef unsigned int __attribute__((address_space(3)))* las_ptr;

// ======== split-K 256x256 GEMM with reg-frag double-buffer (bf16 partials out) ========
// 8 waves, depth-4 ring, counted vmcnt(4).  grid 256 = 16bm x 4bn x 4ks.
// XCD map: wg = (c&7) + 8*bm + 128*(c>>3), c = ks*4+bn -> each XCD serves ONE bn.
// launch_bounds(512,1): VGPR cap >= 256 so BOTH frag sets stay live (round-10's
// (512,2) was interpreted as 4 waves/SIMD -> cap 128 -> dbuf silently destroyed).
__global__ __launch_bounds__(512, 1) void gemm_split_kernel(
        const unsigned short* __restrict__ A,   // S x K bf16, row-major
        const unsigned short* __restrict__ B,   // N x K bf16, row-major
        unsigned short* __restrict__ P) {       // KS x (S*N) bf16 partials
    __shared__ __align__(16) char lds[NBUF2 * TILE2];   // 128 KB
    const int tid  = threadIdx.x;
    const int l    = tid & 63;
    const int w    = tid >> 6;         // 0..7
    const int wg   = blockIdx.x;
    const int x7   = wg & 7;
    const int bm   = (wg >> 3) & 15;
    const int c    = x7 + ((wg >> 7) << 3);    // 0..15
    const int ks   = c >> 2;
    const int bn   = c & 3;
    const int wr = w >> 1, wc = w & 1; // wave owns 64(row) x 128(col)
    const int lcol = l & 15, lk = l >> 4;

    // ---- staging (rule #21): linear LDS dest, pre-swizzled global source ----
    // tile: rows 0..255 = A (16KB), 256..511 = B (16KB); row = 64B, 4 x 16B chunks
    const int kg = (l & 3) ^ ((l >> 3) & 3);
    const unsigned short* srcA0 = A + (size_t)(bm * BM2 + w * 16 + (l >> 2)) * K_DIM
                                    + ks * KSL + kg * 8;
    const unsigned short* srcA1 = srcA0 + (size_t)128 * K_DIM;
    const unsigned short* srcB0 = B + (size_t)(bn * BN2 + w * 16 + (l >> 2)) * K_DIM
                                    + ks * KSL + kg * 8;
    const unsigned short* srcB1 = srcB0 + (size_t)128 * K_DIM;
    const int dst0 = (w * 16 + (l >> 2)) * 64 + (l & 3) * 16;   // + i*8192 per slab

    // ---- fragment read bases (verified conflict-free swizzle); frag offs compile-time ----
    const int swz = (lk ^ ((lcol >> 1) & 3)) << 4;
    const int abase = (wr * 64 + lcol) * 64 + swz;               // + m*1024
    const int bbase = 16384 + (wc * 128 + lcol) * 64 + swz;      // + n*1024

    f32x4 acc[4][8] = {};
    bf16x8 a0[4], b0[8], a1[4], b1[8];     // two statically-named frag sets (rule #20)

#define GLOAD(p_, o_) __builtin_amdgcn_global_load_lds((gas_ptr)(const void*)(p_), \
        (las_ptr)(void*)(lds + (o_)), 16, 0, 0)
#define STAGE2(T, BUFI) { const int _ko = (T) * BK; const int _bo = (BUFI) * TILE2;  \
        GLOAD(srcA0 + _ko, _bo + dst0);         GLOAD(srcA1 + _ko, _bo + dst0 + 8192); \
        GLOAD(srcB0 + _ko, _bo + dst0 + 16384); GLOAD(srcB1 + _ko, _bo + dst0 + 24576); }
#define READF2(RBUF, AR, BR) { const char* _rb = lds + (RBUF) * TILE2;               \
        _Pragma("unroll") for (int m = 0; m < 4; ++m)                                \
            AR[m] = *reinterpret_cast<const bf16x8*>(_rb + abase + m * 1024);        \
        _Pragma("unroll") for (int n = 0; n < 8; ++n)                                \
            BR[n] = *reinterpret_cast<const bf16x8*>(_rb + bbase + n * 1024); }
#define MFMAS2(AMM, BMM) {                                                           \
        __builtin_amdgcn_s_setprio(1);                                               \
        _Pragma("unroll") for (int m = 0; m < 4; ++m)                                \
            _Pragma("unroll") for (int n = 0; n < 8; ++n)                            \
                acc[m][n] = __builtin_amdgcn_mfma_f32_16x16x32_bf16(AMM[m], BMM[n],  \
                                                                    acc[m][n], 0, 0, 0); \
        __builtin_amdgcn_s_setprio(0); }
// Step T: vmcnt(4) -> tile T+1 landed; barrier publishes it and frees buf[(T+3)&3]
// (tile T-1: its frags were read at T-2, consumed by MFMAs at T-1); stage tile T+3;
// read frags(T+1) into the spare set; sched_barrier(0) pins those ds_reads BEFORE
// the MFMA cluster (compiler must not sink them); MFMA frags(T) - no lgkm wait
// needed (read last step), so the new reads fly under the MFMA cluster.
#define BODY2(RBUF, TS, SBUF, WAITN, DOSTAGE, AR, BR, AMM, BMM) {                    \
        asm volatile("s_waitcnt vmcnt(" #WAITN ")" ::: "memory");                    \
        __builtin_amdgcn_s_barrier();                                                \
        if (DOSTAGE) STAGE2(TS, SBUF);                                               \
        READF2(RBUF, AR, BR);                                                        \
        __builtin_amdgcn_sched_barrier(0);                                           \
        MFMAS2(AMM, BMM); }

    STAGE2(0, 0); STAGE2(1, 1); STAGE2(2, 2);       // 12 loads/thread in flight
    asm volatile("s_waitcnt vmcnt(8)" ::: "memory"); // tile 0 landed
    __builtin_amdgcn_s_barrier();
    READF2(0, a0, b0);
    for (int t4 = 0; t4 < NT2 - 4; t4 += 4) {        // T = 0..27, stages 3..30
        BODY2(1, t4 + 3, 3, 4, 1, a1, b1, a0, b0);   // T = t4+0
        BODY2(2, t4 + 4, 0, 4, 1, a0, b0, a1, b1);   // T = t4+1
        BODY2(3, t4 + 5, 1, 4, 1, a1, b1, a0, b0);   // T = t4+2
        BODY2(0, t4 + 6, 2, 4, 1, a0, b0, a1, b1);   // T = t4+3
    }
    BODY2(1, 31, 3, 4, 1, a1, b1, a0, b0);           // T=28, stage last tile (31)
    BODY2(2, 0, 0, 4, 0, a0, b0, a1, b1);            // T=29: tile 30 landed
    BODY2(3, 0, 0, 0, 0, a1, b1, a0, b0);            // T=30: tile 31 landed
    MFMAS2(a1, b1);                                  // T=31
#undef BODY2
#undef MFMAS2
#undef READF2
#undef STAGE2

    // ---- epilogue: bf16 partial store; C/D: col=lane&15, row=(lane>>4)*4+j ----
    unsigned short* Pk = P + (size_t)ks * ((size_t)S_DIM * N_DIM);
    const int col_base = bn * BN2 + wc * 128;
    #pragma unroll
    for (int m = 0; m < 4; ++m) {
        const int row0 = bm * BM2 + wr * 64 + m * 16 + lk * 4;
        #pragma unroll
        for (int n = 0; n < 8; ++n) {
            const int col = col_base + n * 16 + lcol;
            #pragma unroll
            for (int j = 0; j < 4; ++j)
                Pk[(size_t)(row0 + j) * N_DIM + col] = f2bf(acc[m][n][j]);
        }
    }
#undef GLOAD
}

// ---- reduce: out = log(sum_ks P_ks) - lz[col] ----
__global__ void reduce_kernel(const unsigned short* __restrict__ P,
                              const float* __restrict__ lz,
                              float* __restrict__ out) {
    const size_t SN = (size_t)S_DIM * N_DIM;
    int i = blockIdx.x * blockDim.x + threadIdx.x;       // 0 .. SN/8-1
    size_t e = (size_t)i * 8;
    int n = (int)(e & (N_DIM - 1));
    u16x8 p0 = *reinterpret_cast<const u16x8*>(P + e);
    u16x8 p1 = *reinterpret_cast<const u16x8*>(P + SN + e);
    u16x8 p2 = *reinterpret_cast<const u16x8*>(P + 2 * SN + e);
    u16x8 p3 = *reinterpret_cast<const u16x8*>(P + 3 * SN + e);
    float4 lz0 = *reinterpret_cast<const float4*>(lz + n);
    float4 lz1 = *reinterpret_cast<const float4*>(lz + n + 4);
    float lzv[8] = {lz0.x, lz0.y, lz0.z, lz0.w, lz1.x, lz1.y, lz1.z, lz1.w};
    float o[8];
    #pragma unroll
    for (int j = 0; j < 8; ++j) {
        float s = bf2f((unsigned short)p0[j]) + bf2f((unsigned short)p1[j])
                + bf2f((unsigned short)p2[j]) + bf2f((unsigned short)p3[j]);
        o[j] = __logf(s) - lzv[j];
    }
    *reinterpret_cast<float4*>(out + e)     = make_float4(o[0], o[1], o[2], o[3]);
    *reinterpret_cast<float4*>(out + e + 4) = make_float4(o[4], o[5], o[6], o[7]);
}

// ======== fallback: round-5 128x128 (verified 46us) ========
__global__ __launch_bounds__(256, 1) void gemm_log_kernel128(
        const unsigned short* __restrict__ A,
        const unsigned short* __restrict__ B,
        const float* __restrict__ lz,
        float* __restrict__ out) {
    __shared__ __align__(16) char lds[NBUF1 * TILE1];
    const int tid  = threadIdx.x;
    const int l    = tid & 63;
    const int w    = tid >> 6;
    const int bn = blockIdx.x & 7;
    const int bm = blockIdx.x >> 3;
    const int wr = w >> 1, wc = w & 1;
    const int lcol = l & 15, lk = l >> 4;

    const int kg = (l & 3) ^ ((l >> 3) & 3);
    const unsigned short* src[4];
    int dst[4];
    #pragma unroll
    for (int i = 0; i < 4; ++i) {
        const int ri  = w * 4 + i;
        const int row = ri * 16 + (l >> 2);
        src[i] = (ri < 8)
            ? A + (size_t)(bm * BM1 + row) * K_DIM + kg * 8
            : B + (size_t)(bn * BN1 + row - 128) * K_DIM + kg * 8;
        dst[i] = row * 64 + (l & 3) * 16;
    }
    const int swz = (lk ^ ((lcol >> 1) & 3)) << 4;
    int aoff[4], boff[4];
    #pragma unroll
    for (int m = 0; m < 4; ++m) aoff[m] = (wr * 64 + m * 16 + lcol) * 64 + swz;
    #pragma unroll
    for (int n = 0; n < 4; ++n) boff[n] = 8192 + (wc * 64 + n * 16 + lcol) * 64 + swz;

    f32x4 acc[4][4] = {};
    bf16x8 a0[4], b0[4], a1[4], b1[4];

#define GLOAD(p_, o_) __builtin_amdgcn_global_load_lds((gas_ptr)(const void*)(p_), \
        (las_ptr)(void*)(lds + (o_)), 16, 0, 0)
#define STAGE(T, BUFI) { const int _ko = (T) * BK; const int _bo = (BUFI) * TILE1; \
        GLOAD(src[0] + _ko, _bo + dst[0]); GLOAD(src[1] + _ko, _bo + dst[1]);      \
        GLOAD(src[2] + _ko, _bo + dst[2]); GLOAD(src[3] + _ko, _bo + dst[3]); }
#define READF(RBUF, AR, BR) { const char* _rb = lds + (RBUF) * TILE1;              \
        _Pragma("unroll") for (int m = 0; m < 4; ++m)                              \
            AR[m] = *reinterpret_cast<const bf16x8*>(_rb + aoff[m]);               \
        _Pragma("unroll") for (int n = 0; n < 4; ++n)                              \
            BR[n] = *reinterpret_cast<const bf16x8*>(_rb + boff[n]); }
#define MFMAS(AMM, BMM)                                                            \
        _Pragma("unroll") for (int m = 0; m < 4; ++m)                              \
            _Pragma("unroll") for (int n = 0; n < 4; ++n)                          \
                acc[m][n] = __builtin_amdgcn_mfma_f32_16x16x32_bf16(AMM[m], BMM[n],\
                                                                    acc[m][n], 0, 0, 0);
#define BODY(T, SB, RB, WAITN, DOSTAGE, AR, BR, AMM, BMM) {                        \
        asm volatile("s_waitcnt vmcnt(" #WAITN ")" ::: "memory");                  \
        __builtin_amdgcn_s_barrier();                                              \
        if (DOSTAGE) STAGE((T) + 8, SB);                                           \
        READF(RB, AR, BR);                                                         \
        MFMAS(AMM, BMM); }

    STAGE(0, 0); STAGE(1, 1); STAGE(2, 2); STAGE(3, 3);
    STAGE(4, 4); STAGE(5, 5); STAGE(6, 6); STAGE(7, 7);
    asm volatile("s_waitcnt vmcnt(28)" ::: "memory");
    __builtin_amdgcn_s_barrier();
    READF(0, a0, b0);
    for (int t8 = 0; t8 < NT1 - 8; t8 += 8) {
        BODY(t8 + 0, 0, 1, 24, 1, a1, b1, a0, b0);
        BODY(t8 + 1, 1, 2, 24, 1, a0, b0, a1, b1);
        BODY(t8 + 2, 2, 3, 24, 1, a1, b1, a0, b0);
        BODY(t8 + 3, 3, 4, 24, 1, a0, b0, a1, b1);
        BODY(t8 + 4, 4, 5, 24, 1, a1, b1, a0, b0);
        BODY(t8 + 5, 5, 6, 24, 1, a0, b0, a1, b1);
        BODY(t8 + 6, 6, 7, 24, 1, a1, b1, a0, b0);
        BODY(t8 + 7, 7, 0, 24, 1, a0, b0, a1, b1);
    }
    BODY(120, 0, 1, 24, 0, a1, b1, a0, b0);
    BODY(121, 1, 2, 20, 0, a0, b0, a1, b1);
    BODY(122, 2, 3, 16, 0, a1, b1, a0, b0);
    BODY(123, 3, 4, 12, 0, a0, b0, a1, b1);
    BODY(124, 4, 5,  8, 0, a1, b1, a0, b0);
    BODY(125, 5, 6,  4, 0, a0, b0, a1, b1);
    BODY(126, 6, 7,  0, 0, a1, b1, a0, b0);
    MFMAS(a1, b1);
#undef BODY
#undef MFMAS
#undef READF
#undef STAGE
#undef GLOAD

    const int col_base = bn * BN1 + wc * 64;
    float lzv[4];
    #pragma unroll
    for (int n = 0; n < 4; ++n) lzv[n] = lz[col_base + n * 16 + lcol];
    #pragma unroll
    for (int m = 0; m < 4; ++m) {
        const int row0 = bm * BM1 + wr * 64 + m * 16 + lk * 4;
        #pragma unroll
        for (int n = 0; n < 4; ++n) {
            const int col = col_base + n * 16 + lcol;
            #pragma unroll
            for (int j = 0; j < 4; ++j)
                out[(size_t)(row0 + j) * N_DIM + col] = __logf(acc[m][n][j]) - lzv[n];
        }
    }
}

// ---------------- emergency fallback (no workspace) ----------------
__global__ void naive_kernel(const float* __restrict__ ll1, const float* __restrict__ ll2,
                             const float* __restrict__ w1, const float* __restrict__ w2,
                             float* __restrict__ out) {
    int idx = blockIdx.x * blockDim.x + threadIdx.x;
    if (idx >= S_DIM * N_DIM) return;
    int s = idx >> 10, n = idx & (N_DIM - 1);
    const float* a1 = ll1 + (size_t)s * C_DIM;
    const float* a2 = ll2 + (size_t)s * C_DIM;
    const float* b1 = w1 + (size_t)n * C_DIM;
    const float* b2 = w2 + (size_t)n * C_DIM;
    float mx = -3.0e38f;
    for (int c = 0; c < C_DIM; ++c) mx = fmaxf(mx, b1[c]);
    for (int c = 0; c < C_DIM; ++c) mx = fmaxf(mx, b2[c]);
    float zs = 0.f, acc = 0.f;
    for (int c = 0; c < C_DIM; ++c) { zs += __expf(b1[c] - mx); acc += __expf(a1[c] + b1[c]); }
    for (int c = 0; c < C_DIM; ++c) { zs += __expf(b2[c] - mx); acc += __expf(a2[c] + b2[c]); }
    out[idx] = __logf(acc) - (mx + __logf(zs));
}

extern "C" void kernel_launch(void* const* d_in, const int* in_sizes, int n_in,
                              void* d_out, int out_size, void* d_ws, size_t ws_size,
                              hipStream_t stream) {
    const float* ll1 = (const float*)d_in[0];
    const float* ll2 = (const float*)d_in[1];
    const float* w1  = (const float*)d_in[2];
    const float* w2  = (const float*)d_in[3];
    float* out = (float*)d_out;

    const size_t a_elems = (size_t)S_DIM * K_DIM;
    const size_t b_elems = (size_t)N_DIM * K_DIM;
    const size_t sn      = (size_t)S_DIM * N_DIM;
    const size_t need1 = (a_elems + b_elems) * sizeof(unsigned short) + N_DIM * sizeof(float);
    const size_t need2 = need1 + KS * sn * sizeof(unsigned short);
    if (ws_size < need1) {
        naive_kernel<<<(S_DIM * N_DIM + 255) / 256, 256, 0, stream>>>(ll1, ll2, w1, w2, out);
        return;
    }
    unsigned short* Aws = (unsigned short*)d_ws;
    unsigned short* Bws = Aws + a_elems;
    float* lzws = (float*)(Bws + b_elems);

    exp_ll_kernel<<<2048, 256, 0, stream>>>(ll1, ll2, Aws);
    w_kernel<<<N_DIM, 256, 0, stream>>>(w1, w2, Bws, lzws);

    if (ws_size >= need2) {
        unsigned short* Pws = (unsigned short*)(lzws + N_DIM);
        gemm_split_kernel<<<(S_DIM / BM2) * (N_DIM / BN2) * KS, 512, 0, stream>>>(Aws, Bws, Pws);
        reduce_kernel<<<(int)(sn / 8 / 256), 256, 0, stream>>>(Pws, lzws, out);
    } else {
        gemm_log_kernel128<<<(S_DIM / BM1) * (N_DIM / BN1), 256, 0, stream>>>(Aws, Bws, lzws, out);
    }
}

// Round 12
// 73.853 us; speedup vs baseline: 1.0685x; 1.0685x over previous
//
#include <hip/hip_runtime.h>

#define S_DIM 4096
#define C_DIM 2048      // C1 == C2
#define N_DIM 1024
#define K_DIM 4096      // C1 + C2

// ---- split-K 256x256 GEMM ----
#define BM2 256
#define BN2 256
#define KS 4                    // K splits
#define KSL (K_DIM / KS)        // 1024 K per split
#define BK 32
#define NT2 (KSL / BK)          // 32 steps
#define TILE2 32768             // (256 A + 256 B rows) * 64 B
#define NBUF2 5                 // 160 KB LDS ring (full CU allotment)

// ---- fallback 128x128 (round-5, verified 46us) ----
#define BM1 128
#define BN1 128
#define NT1 (K_DIM / BK)        // 128
#define TILE1 16384
#define NBUF1 8

typedef __attribute__((ext_vector_type(8))) short bf16x8;
typedef __attribute__((ext_vector_type(8))) unsigned short u16x8;
typedef __attribute__((ext_vector_type(4))) float f32x4;

__device__ static inline unsigned short f2bf(float f) {
    unsigned int u = __float_as_uint(f);
    u += 0x7FFFu + ((u >> 16) & 1u);
    return (unsigned short)(u >> 16);
}
__device__ static inline float bf2f(unsigned short h) {
    return __uint_as_float((unsigned int)h << 16);
}

// ---------------- exp + cast to bf16 for A (both ll sources, one launch) ----------------
__global__ void exp_ll_kernel(const float* __restrict__ ll1,
                              const float* __restrict__ ll2,
                              unsigned short* __restrict__ A) {
    const int total4 = S_DIM * C_DIM / 4;
    int stride = gridDim.x * blockDim.x;
    for (int i = blockIdx.x * blockDim.x + threadIdx.x; i < total4; i += stride) {
        int e = i << 2;
        int r = e >> 11;          // src cols = 2048
        int c = e & 2047;
        size_t dst = ((size_t)r << 12) + c;
        float4 v = *reinterpret_cast<const float4*>(ll1 + e);
        ushort4 o;
        o.x = f2bf(__expf(v.x)); o.y = f2bf(__expf(v.y));
        o.z = f2bf(__expf(v.z)); o.w = f2bf(__expf(v.w));
        *reinterpret_cast<ushort4*>(A + dst) = o;
        float4 u = *reinterpret_cast<const float4*>(ll2 + e);
        ushort4 p;
        p.x = f2bf(__expf(u.x)); p.y = f2bf(__expf(u.y));
        p.z = f2bf(__expf(u.z)); p.w = f2bf(__expf(u.w));
        *reinterpret_cast<ushort4*>(A + dst + C_DIM) = p;
    }
}

// ---------------- w: exp->B (bf16) AND per-row logsumexp, fused ----------------
__global__ void w_kernel(const float* __restrict__ w1,
                         const float* __restrict__ w2,
                         unsigned short* __restrict__ B,
                         float* __restrict__ lz) {
    const int n = blockIdx.x;
    const int tid = threadIdx.x;          // 0..255
    const int lane = tid & 63, wv = tid >> 6;
    const float* r1 = w1 + ((size_t)n << 11);
    const float* r2 = w2 + ((size_t)n << 11);
    float4 v0 = *reinterpret_cast<const float4*>(r1 + tid * 8);
    float4 v1 = *reinterpret_cast<const float4*>(r1 + tid * 8 + 4);
    float4 u0 = *reinterpret_cast<const float4*>(r2 + tid * 8);
    float4 u1 = *reinterpret_cast<const float4*>(r2 + tid * 8 + 4);

    float mx = fmaxf(fmaxf(fmaxf(v0.x, v0.y), fmaxf(v0.z, v0.w)),
                     fmaxf(fmaxf(v1.x, v1.y), fmaxf(v1.z, v1.w)));
    mx = fmaxf(mx, fmaxf(fmaxf(fmaxf(u0.x, u0.y), fmaxf(u0.z, u0.w)),
                          fmaxf(fmaxf(u1.x, u1.y), fmaxf(u1.z, u1.w))));
    #pragma unroll
    for (int off = 32; off > 0; off >>= 1) mx = fmaxf(mx, __shfl_xor(mx, off));
    __shared__ float red[4];
    if (lane == 0) red[wv] = mx;
    __syncthreads();
    mx = fmaxf(fmaxf(red[0], red[1]), fmaxf(red[2], red[3]));

    float s = __expf(v0.x - mx) + __expf(v0.y - mx) + __expf(v0.z - mx) + __expf(v0.w - mx)
            + __expf(v1.x - mx) + __expf(v1.y - mx) + __expf(v1.z - mx) + __expf(v1.w - mx)
            + __expf(u0.x - mx) + __expf(u0.y - mx) + __expf(u0.z - mx) + __expf(u0.w - mx)
            + __expf(u1.x - mx) + __expf(u1.y - mx) + __expf(u1.z - mx) + __expf(u1.w - mx);
    #pragma unroll
    for (int off = 32; off > 0; off >>= 1) s += __shfl_xor(s, off);
    __shared__ float red2[4];
    if (lane == 0) red2[wv] = s;
    __syncthreads();
    if (tid == 0)
        lz[n] = mx + __logf(red2[0] + red2[1] + red2[2] + red2[3]);

    unsigned short* brow = B + ((size_t)n << 12);
    ushort4 o;
    o.x = f2bf(__expf(v0.x)); o.y = f2bf(__expf(v0.y));
    o.z = f2bf(__expf(v0.z)); o.w = f2bf(__expf(v0.w));
    *reinterpret_cast<ushort4*>(brow + tid * 8) = o;
    o.x = f2bf(__expf(v1.x)); o.y = f2bf(__expf(v1.y));
    o.z = f2bf(__expf(v1.z)); o.w = f2bf(__expf(v1.w));
    *reinterpret_cast<ushort4*>(brow + tid * 8 + 4) = o;
    o.x = f2bf(__expf(u0.x)); o.y = f2bf(__expf(u0.y));
    o.z = f2bf(__expf(u0.z)); o.w = f2bf(__expf(u0.w));
    *reinterpret_cast<ushort4*>(brow + C_DIM + tid * 8) = o;
    o.x = f2bf(__expf(u1.x)); o.y = f2bf(__expf(u1.y));
    o.z = f2bf(__expf(u1.z)); o.w = f2bf(__expf(u1.w));
    *reinterpret_cast<ushort4*>(brow + C_DIM + tid * 8 + 4) = o;
}

typedef const unsigned int __attribute__((address_space(1)))* gas_ptr;
typedef unsigned int __attribute__((address_space(3)))* las_ptr;

// ======== split-K 256x256 GEMM, depth-5 ring (160KB), vmcnt(12) ========
// Round-9 structure (read tile T, MFMA tile T, single frag set) with one change:
// NBUF 4->5 and stage T+4 (outstanding window 48->64KB/CU).
// 8 waves; grid 256 = 16bm x 4bn x 4ks; XCD map: each XCD serves ONE bn.
__global__ __launch_bounds__(512, 1) void gemm_split_kernel(
        const unsigned short* __restrict__ A,   // S x K bf16, row-major
        const unsigned short* __restrict__ B,   // N x K bf16, row-major
        unsigned short* __restrict__ P) {       // KS x (S*N) bf16 partials
    __shared__ __align__(16) char lds[NBUF2 * TILE2];   // 160 KB
    const int tid  = threadIdx.x;
    const int l    = tid & 63;
    const int w    = tid >> 6;         // 0..7
    const int wg   = blockIdx.x;
    const int x7   = wg & 7;
    const int bm   = (wg >> 3) & 15;
    const int c    = x7 + ((wg >> 7) << 3);    // 0..15
    const int ks   = c >> 2;
    const int bn   = c & 3;
    const int wr = w >> 1, wc = w & 1; // wave owns 64(row) x 128(col)
    const int lcol = l & 15, lk = l >> 4;

    // ---- staging (rule #21): linear LDS dest, pre-swizzled global source ----
    // tile: rows 0..255 = A (16KB), 256..511 = B (16KB); row = 64B, 4 x 16B chunks
    const int kg = (l & 3) ^ ((l >> 3) & 3);
    const unsigned short* srcA0 = A + (size_t)(bm * BM2 + w * 16 + (l >> 2)) * K_DIM
                                    + ks * KSL + kg * 8;
    const unsigned short* srcA1 = srcA0 + (size_t)128 * K_DIM;
    const unsigned short* srcB0 = B + (size_t)(bn * BN2 + w * 16 + (l >> 2)) * K_DIM
                                    + ks * KSL + kg * 8;
    const unsigned short* srcB1 = srcB0 + (size_t)128 * K_DIM;
    const int dst0 = (w * 16 + (l >> 2)) * 64 + (l & 3) * 16;   // + i*8192 per slab

    // ---- fragment read bases (verified conflict-free swizzle) ----
    const int swz = (lk ^ ((lcol >> 1) & 3)) << 4;
    const int abase = (wr * 64 + lcol) * 64 + swz;               // + m*1024
    const int bbase = 16384 + (wc * 128 + lcol) * 64 + swz;      // + n*1024

    f32x4 acc[4][8] = {};
    bf16x8 a[4], b[8];      // single frag set (round-9 verified structure)

#define GLOAD(p_, o_) __builtin_amdgcn_global_load_lds((gas_ptr)(const void*)(p_), \
        (las_ptr)(void*)(lds + (o_)), 16, 0, 0)
#define STAGE2(T, BO) { const int _ko = (T) * BK; const int _bo = (BO);              \
        GLOAD(srcA0 + _ko, _bo + dst0);         GLOAD(srcA1 + _ko, _bo + dst0 + 8192); \
        GLOAD(srcB0 + _ko, _bo + dst0 + 16384); GLOAD(srcB1 + _ko, _bo + dst0 + 24576); }
#define READF2(BO) { const char* _rb = lds + (BO);                                   \
        _Pragma("unroll") for (int m = 0; m < 4; ++m)                                \
            a[m] = *reinterpret_cast<const bf16x8*>(_rb + abase + m * 1024);         \
        _Pragma("unroll") for (int n = 0; n < 8; ++n)                                \
            b[n] = *reinterpret_cast<const bf16x8*>(_rb + bbase + n * 1024); }
#define MFMAS2() {                                                                   \
        __builtin_amdgcn_s_setprio(1);                                               \
        _Pragma("unroll") for (int m = 0; m < 4; ++m)                                \
            _Pragma("unroll") for (int n = 0; n < 8; ++n)                            \
                acc[m][n] = __builtin_amdgcn_mfma_f32_16x16x32_bf16(a[m], b[n],      \
                                                                    acc[m][n], 0, 0, 0); \
        __builtin_amdgcn_s_setprio(0); }
// Step T: vmcnt(12) -> tile T landed (tiles T+1..T+3 may stay in flight); barrier
// frees buf[(T+4)%5] (tile T-1 was consumed at step T-1); stage tile T+4 there;
// read frags(T); MFMA (compiler interleaves ds_read returns with MFMA issue).
#define BODY2(RBO, TS, SBO, WAITN, DOSTAGE) {                                        \
        asm volatile("s_waitcnt vmcnt(" #WAITN ")" ::: "memory");                    \
        __builtin_amdgcn_s_barrier();                                                \
        if (DOSTAGE) STAGE2(TS, SBO);                                                \
        READF2(RBO);                                                                 \
        MFMAS2(); }

    // prologue: fill 4 of 5 ring slots (16 loads in flight)
    STAGE2(0, 0); STAGE2(1, TILE2); STAGE2(2, 2 * TILE2); STAGE2(3, 3 * TILE2);
    int rbo = 0;                   // read-buf byte offset, cycles 0..4*TILE2
    int sbo = 4 * TILE2;           // stage-buf byte offset
    for (int T = 0; T < NT2 - 4; ++T) {            // T = 0..27, stages 4..31
        BODY2(rbo, T + 4, sbo, 12, 1);
        rbo += TILE2; if (rbo == NBUF2 * TILE2) rbo = 0;
        sbo += TILE2; if (sbo == NBUF2 * TILE2) sbo = 0;
    }
    BODY2(rbo, 0, 0, 12, 0); rbo += TILE2; if (rbo == NBUF2 * TILE2) rbo = 0;  // T=28
    BODY2(rbo, 0, 0, 8, 0);  rbo += TILE2; if (rbo == NBUF2 * TILE2) rbo = 0;  // T=29
    BODY2(rbo, 0, 0, 4, 0);  rbo += TILE2; if (rbo == NBUF2 * TILE2) rbo = 0;  // T=30
    BODY2(rbo, 0, 0, 0, 0);                                                    // T=31
#undef BODY2
#undef MFMAS2
#undef READF2
#undef STAGE2

    // ---- epilogue: bf16 partial store; C/D: col=lane&15, row=(lane>>4)*4+j ----
    unsigned short* Pk = P + (size_t)ks * ((size_t)S_DIM * N_DIM);
    const int col_base = bn * BN2 + wc * 128;
    #pragma unroll
    for (int m = 0; m < 4; ++m) {
        const int row0 = bm * BM2 + wr * 64 + m * 16 + lk * 4;
        #pragma unroll
        for (int n = 0; n < 8; ++n) {
            const int col = col_base + n * 16 + lcol;
            #pragma unroll
            for (int j = 0; j < 4; ++j)
                Pk[(size_t)(row0 + j) * N_DIM + col] = f2bf(acc[m][n][j]);
        }
    }
#undef GLOAD
}

// ---- reduce: out = log(sum_ks P_ks) - lz[col] ----
__global__ void reduce_kernel(const unsigned short* __restrict__ P,
                              const float* __restrict__ lz,
                              float* __restrict__ out) {
    const size_t SN = (size_t)S_DIM * N_DIM;
    int i = blockIdx.x * blockDim.x + threadIdx.x;       // 0 .. SN/8-1
    size_t e = (size_t)i * 8;
    int n = (int)(e & (N_DIM - 1));
    u16x8 p0 = *reinterpret_cast<const u16x8*>(P + e);
    u16x8 p1 = *reinterpret_cast<const u16x8*>(P + SN + e);
    u16x8 p2 = *reinterpret_cast<const u16x8*>(P + 2 * SN + e);
    u16x8 p3 = *reinterpret_cast<const u16x8*>(P + 3 * SN + e);
    float4 lz0 = *reinterpret_cast<const float4*>(lz + n);
    float4 lz1 = *reinterpret_cast<const float4*>(lz + n + 4);
    float lzv[8] = {lz0.x, lz0.y, lz0.z, lz0.w, lz1.x, lz1.y, lz1.z, lz1.w};
    float o[8];
    #pragma unroll
    for (int j = 0; j < 8; ++j) {
        float s = bf2f((unsigned short)p0[j]) + bf2f((unsigned short)p1[j])
                + bf2f((unsigned short)p2[j]) + bf2f((unsigned short)p3[j]);
        o[j] = __logf(s) - lzv[j];
    }
    *reinterpret_cast<float4*>(out + e)     = make_float4(o[0], o[1], o[2], o[3]);
    *reinterpret_cast<float4*>(out + e + 4) = make_float4(o[4], o[5], o[6], o[7]);
}

// ======== fallback: round-5 128x128 (verified 46us) ========
__global__ __launch_bounds__(256, 1) void gemm_log_kernel128(
        const unsigned short* __restrict__ A,
        const unsigned short* __restrict__ B,
        const float* __restrict__ lz,
        float* __restrict__ out) {
    __shared__ __align__(16) char lds[NBUF1 * TILE1];
    const int tid  = threadIdx.x;
    const int l    = tid & 63;
    const int w    = tid >> 6;
    const int bn = blockIdx.x & 7;
    const int bm = blockIdx.x >> 3;
    const int wr = w >> 1, wc = w & 1;
    const int lcol = l & 15, lk = l >> 4;

    const int kg = (l & 3) ^ ((l >> 3) & 3);
    const unsigned short* src[4];
    int dst[4];
    #pragma unroll
    for (int i = 0; i < 4; ++i) {
        const int ri  = w * 4 + i;
        const int row = ri * 16 + (l >> 2);
        src[i] = (ri < 8)
            ? A + (size_t)(bm * BM1 + row) * K_DIM + kg * 8
            : B + (size_t)(bn * BN1 + row - 128) * K_DIM + kg * 8;
        dst[i] = row * 64 + (l & 3) * 16;
    }
    const int swz = (lk ^ ((lcol >> 1) & 3)) << 4;
    int aoff[4], boff[4];
    #pragma unroll
    for (int m = 0; m < 4; ++m) aoff[m] = (wr * 64 + m * 16 + lcol) * 64 + swz;
    #pragma unroll
    for (int n = 0; n < 4; ++n) boff[n] = 8192 + (wc * 64 + n * 16 + lcol) * 64 + swz;

    f32x4 acc[4][4] = {};
    bf16x8 a0[4], b0[4], a1[4], b1[4];

#define GLOAD(p_, o_) __builtin_amdgcn_global_load_lds((gas_ptr)(const void*)(p_), \
        (las_ptr)(void*)(lds + (o_)), 16, 0, 0)
#define STAGE(T, BUFI) { const int _ko = (T) * BK; const int _bo = (BUFI) * TILE1; \
        GLOAD(src[0] + _ko, _bo + dst[0]); GLOAD(src[1] + _ko, _bo + dst[1]);      \
        GLOAD(src[2] + _ko, _bo + dst[2]); GLOAD(src[3] + _ko, _bo + dst[3]); }
#define READF(RBUF, AR, BR) { const char* _rb = lds + (RBUF) * TILE1;              \
        _Pragma("unroll") for (int m = 0; m < 4; ++m)                              \
            AR[m] = *reinterpret_cast<const bf16x8*>(_rb + aoff[m]);               \
        _Pragma("unroll") for (int n = 0; n < 4; ++n)                              \
            BR[n] = *reinterpret_cast<const bf16x8*>(_rb + boff[n]); }
#define MFMAS(AMM, BMM)                                                            \
        _Pragma("unroll") for (int m = 0; m < 4; ++m)                              \
            _Pragma("unroll") for (int n = 0; n < 4; ++n)                          \
                acc[m][n] = __builtin_amdgcn_mfma_f32_16x16x32_bf16(AMM[m], BMM[n],\
                                                                    acc[m][n], 0, 0, 0);
#define BODY(T, SB, RB, WAITN, DOSTAGE, AR, BR, AMM, BMM) {                        \
        asm volatile("s_waitcnt vmcnt(" #WAITN ")" ::: "memory");                  \
        __builtin_amdgcn_s_barrier();                                              \
        if (DOSTAGE) STAGE((T) + 8, SB);                                           \
        READF(RB, AR, BR);                                                         \
        MFMAS(AMM, BMM); }

    STAGE(0, 0); STAGE(1, 1); STAGE(2, 2); STAGE(3, 3);
    STAGE(4, 4); STAGE(5, 5); STAGE(6, 6); STAGE(7, 7);
    asm volatile("s_waitcnt vmcnt(28)" ::: "memory");
    __builtin_amdgcn_s_barrier();
    READF(0, a0, b0);
    for (int t8 = 0; t8 < NT1 - 8; t8 += 8) {
        BODY(t8 + 0, 0, 1, 24, 1, a1, b1, a0, b0);
        BODY(t8 + 1, 1, 2, 24, 1, a0, b0, a1, b1);
        BODY(t8 + 2, 2, 3, 24, 1, a1, b1, a0, b0);
        BODY(t8 + 3, 3, 4, 24, 1, a0, b0, a1, b1);
        BODY(t8 + 4, 4, 5, 24, 1, a1, b1, a0, b0);
        BODY(t8 + 5, 5, 6, 24, 1, a0, b0, a1, b1);
        BODY(t8 + 6, 6, 7, 24, 1, a1, b1, a0, b0);
        BODY(t8 + 7, 7, 0, 24, 1, a0, b0, a1, b1);
    }
    BODY(120, 0, 1, 24, 0, a1, b1, a0, b0);
    BODY(121, 1, 2, 20, 0, a0, b0, a1, b1);
    BODY(122, 2, 3, 16, 0, a1, b1, a0, b0);
    BODY(123, 3, 4, 12, 0, a0, b0, a1, b1);
    BODY(124, 4, 5,  8, 0, a1, b1, a0, b0);
    BODY(125, 5, 6,  4, 0, a0, b0, a1, b1);
    BODY(126, 6, 7,  0, 0, a1, b1, a0, b0);
    MFMAS(a1, b1);
#undef BODY
#undef MFMAS
#undef READF
#undef STAGE
#undef GLOAD

    const int col_base = bn * BN1 + wc * 64;
    float lzv[4];
    #pragma unroll
    for (int n = 0; n < 4; ++n) lzv[n] = lz[col_base + n * 16 + lcol];
    #pragma unroll
    for (int m = 0; m < 4; ++m) {
        const int row0 = bm * BM1 + wr * 64 + m * 16 + lk * 4;
        #pragma unroll
        for (int n = 0; n < 4; ++n) {
            const int col = col_base + n * 16 + lcol;
            #pragma unroll
            for (int j = 0; j < 4; ++j)
                out[(size_t)(row0 + j) * N_DIM + col] = __logf(acc[m][n][j]) - lzv[n];
        }
    }
}

// ---------------- emergency fallback (no workspace) ----------------
__global__ void naive_kernel(const float* __restrict__ ll1, const float* __restrict__ ll2,
                             const float* __restrict__ w1, const float* __restrict__ w2,
                             float* __restrict__ out) {
    int idx = blockIdx.x * blockDim.x + threadIdx.x;
    if (idx >= S_DIM * N_DIM) return;
    int s = idx >> 10, n = idx & (N_DIM - 1);
    const float* a1 = ll1 + (size_t)s * C_DIM;
    const float* a2 = ll2 + (size_t)s * C_DIM;
    const float* b1 = w1 + (size_t)n * C_DIM;
    const float* b2 = w2 + (size_t)n * C_DIM;
    float mx = -3.0e38f;
    for (int c = 0; c < C_DIM; ++c) mx = fmaxf(mx, b1[c]);
    for (int c = 0; c < C_DIM; ++c) mx = fmaxf(mx, b2[c]);
    float zs = 0.f, acc = 0.f;
    for (int c = 0; c < C_DIM; ++c) { zs += __expf(b1[c] - mx); acc += __expf(a1[c] + b1[c]); }
    for (int c = 0; c < C_DIM; ++c) { zs += __expf(b2[c] - mx); acc += __expf(a2[c] + b2[c]); }
    out[idx] = __logf(acc) - (mx + __logf(zs));
}

extern "C" void kernel_launch(void* const* d_in, const int* in_sizes, int n_in,
                              void* d_out, int out_size, void* d_ws, size_t ws_size,
                              hipStream_t stream) {
    const float* ll1 = (const float*)d_in[0];
    const float* ll2 = (const float*)d_in[1];
    const float* w1  = (const float*)d_in[2];
    const float* w2  = (const float*)d_in[3];
    float* out = (float*)d_out;

    const size_t a_elems = (size_t)S_DIM * K_DIM;
    const size_t b_elems = (size_t)N_DIM * K_DIM;
    const size_t sn      = (size_t)S_DIM * N_DIM;
    const size_t need1 = (a_elems + b_elems) * sizeof(unsigned short) + N_DIM * sizeof(float);
    const size_t need2 = need1 + KS * sn * sizeof(unsigned short);
    if (ws_size < need1) {
        naive_kernel<<<(S_DIM * N_DIM + 255) / 256, 256, 0, stream>>>(ll1, ll2, w1, w2, out);
        return;
    }
    unsigned short* Aws = (unsigned short*)d_ws;
    unsigned short* Bws = Aws + a_elems;
    float* lzws = (float*)(Bws + b_elems);

    exp_ll_kernel<<<2048, 256, 0, stream>>>(ll1, ll2, Aws);
    w_kernel<<<N_DIM, 256, 0, stream>>>(w1, w2, Bws, lzws);

    if (ws_size >= need2) {
        unsigned short* Pws = (unsigned short*)(lzws + N_DIM);
        gemm_split_kernel<<<(S_DIM / BM2) * (N_DIM / BN2) * KS, 512, 0, stream>>>(Aws, Bws, Pws);
        reduce_kernel<<<(int)(sn / 8 / 256), 256, 0, stream>>>(Pws, lzws, out);
    } else {
        gemm_log_kernel128<<<(S_DIM / BM1) * (N_DIM / BN1), 256, 0, stream>>>(Aws, Bws, lzws, out);
    }
}

// Round 13
// 67.744 us; speedup vs baseline: 1.1649x; 1.0902x over previous
//
#include <hip/hip_runtime.h>

#define S_DIM 4096
#define C_DIM 2048      // C1 == C2
#define N_DIM 1024
#define K_DIM 4096      // C1 + C2

#define BM 128
#define BN 128
#define BK 32
#define NT (K_DIM / BK)         // 128 K-steps
#define TILE_BYTES 16384        // (128 A rows + 128 B rows) * 64 B
#define NBUF 8                  // 128 KB LDS ring

typedef __attribute__((ext_vector_type(8))) short bf16x8;
typedef __attribute__((ext_vector_type(8))) unsigned short u16x8;
typedef __attribute__((ext_vector_type(4))) float f32x4;

__device__ static inline unsigned short f2bf(float f) {
    unsigned int u = __float_as_uint(f);
    u += 0x7FFFu + ((u >> 16) & 1u);
    return (unsigned short)(u >> 16);
}

// ---- fused pre-pass ----
// blocks [0, N_DIM):           per-node w row -> exp(w) into B (bf16) + logsumexp -> lz
// blocks [N_DIM, N_DIM+2048):  exp(ll1), exp(ll2) -> A (bf16), 16B stores
__global__ void prepass_kernel(const float* __restrict__ ll1,
                               const float* __restrict__ ll2,
                               const float* __restrict__ w1,
                               const float* __restrict__ w2,
                               unsigned short* __restrict__ A,
                               unsigned short* __restrict__ B,
                               float* __restrict__ lz) {
    __shared__ float red[4];
    __shared__ float red2[4];
    const int tid = threadIdx.x;

    if (blockIdx.x < N_DIM) {
        // ---------------- w row: exp->B AND logsumexp ----------------
        const int n = blockIdx.x;
        const int lane = tid & 63, wv = tid >> 6;
        const float* r1 = w1 + ((size_t)n << 11);
        const float* r2 = w2 + ((size_t)n << 11);
        float4 v0 = *reinterpret_cast<const float4*>(r1 + tid * 8);
        float4 v1 = *reinterpret_cast<const float4*>(r1 + tid * 8 + 4);
        float4 u0 = *reinterpret_cast<const float4*>(r2 + tid * 8);
        float4 u1 = *reinterpret_cast<const float4*>(r2 + tid * 8 + 4);

        float mx = fmaxf(fmaxf(fmaxf(v0.x, v0.y), fmaxf(v0.z, v0.w)),
                         fmaxf(fmaxf(v1.x, v1.y), fmaxf(v1.z, v1.w)));
        mx = fmaxf(mx, fmaxf(fmaxf(fmaxf(u0.x, u0.y), fmaxf(u0.z, u0.w)),
                              fmaxf(fmaxf(u1.x, u1.y), fmaxf(u1.z, u1.w))));
        #pragma unroll
        for (int off = 32; off > 0; off >>= 1) mx = fmaxf(mx, __shfl_xor(mx, off));
        if (lane == 0) red[wv] = mx;
        __syncthreads();
        mx = fmaxf(fmaxf(red[0], red[1]), fmaxf(red[2], red[3]));

        float s = __expf(v0.x - mx) + __expf(v0.y - mx) + __expf(v0.z - mx) + __expf(v0.w - mx)
                + __expf(v1.x - mx) + __expf(v1.y - mx) + __expf(v1.z - mx) + __expf(v1.w - mx)
                + __expf(u0.x - mx) + __expf(u0.y - mx) + __expf(u0.z - mx) + __expf(u0.w - mx)
                + __expf(u1.x - mx) + __expf(u1.y - mx) + __expf(u1.z - mx) + __expf(u1.w - mx);
        #pragma unroll
        for (int off = 32; off > 0; off >>= 1) s += __shfl_xor(s, off);
        if (lane == 0) red2[wv] = s;
        __syncthreads();
        if (tid == 0)
            lz[n] = mx + __logf(red2[0] + red2[1] + red2[2] + red2[3]);

        unsigned short* brow = B + ((size_t)n << 12);
        u16x8 o;
        o[0] = f2bf(__expf(v0.x)); o[1] = f2bf(__expf(v0.y));
        o[2] = f2bf(__expf(v0.z)); o[3] = f2bf(__expf(v0.w));
        o[4] = f2bf(__expf(v1.x)); o[5] = f2bf(__expf(v1.y));
        o[6] = f2bf(__expf(v1.z)); o[7] = f2bf(__expf(v1.w));
        *reinterpret_cast<u16x8*>(brow + tid * 8) = o;
        o[0] = f2bf(__expf(u0.x)); o[1] = f2bf(__expf(u0.y));
        o[2] = f2bf(__expf(u0.z)); o[3] = f2bf(__expf(u0.w));
        o[4] = f2bf(__expf(u1.x)); o[5] = f2bf(__expf(u1.y));
        o[6] = f2bf(__expf(u1.z)); o[7] = f2bf(__expf(u1.w));
        *reinterpret_cast<u16x8*>(brow + C_DIM + tid * 8) = o;
        return;
    }

    // ---------------- exp(ll1), exp(ll2) -> A, 8 elems/tensor/iter ----------------
    const int bid = blockIdx.x - N_DIM;        // 0..2047
    const int total8 = S_DIM * C_DIM / 8;      // 1M
    const int stride = 2048 * 256;
    for (int i = bid * 256 + tid; i < total8; i += stride) {
        int e = i << 3;
        int r = e >> 11;          // src cols = 2048
        int c = e & 2047;
        size_t dst = ((size_t)r << 12) + c;
        float4 v0 = *reinterpret_cast<const float4*>(ll1 + e);
        float4 v1 = *reinterpret_cast<const float4*>(ll1 + e + 4);
        u16x8 o;
        o[0] = f2bf(__expf(v0.x)); o[1] = f2bf(__expf(v0.y));
        o[2] = f2bf(__expf(v0.z)); o[3] = f2bf(__expf(v0.w));
        o[4] = f2bf(__expf(v1.x)); o[5] = f2bf(__expf(v1.y));
        o[6] = f2bf(__expf(v1.z)); o[7] = f2bf(__expf(v1.w));
        *reinterpret_cast<u16x8*>(A + dst) = o;
        float4 u0 = *reinterpret_cast<const float4*>(ll2 + e);
        float4 u1 = *reinterpret_cast<const float4*>(ll2 + e + 4);
        o[0] = f2bf(__expf(u0.x)); o[1] = f2bf(__expf(u0.y));
        o[2] = f2bf(__expf(u0.z)); o[3] = f2bf(__expf(u0.w));
        o[4] = f2bf(__expf(u1.x)); o[5] = f2bf(__expf(u1.y));
        o[6] = f2bf(__expf(u1.z)); o[7] = f2bf(__expf(u1.w));
        *reinterpret_cast<u16x8*>(A + dst + C_DIM) = o;
    }
}

// -- bf16 MFMA GEMM: producer/consumer waves, depth-8 ring, reg-frag pipeline, log-epilogue --
// (byte-identical to round-7's verified 46.4us kernel)
typedef const unsigned int __attribute__((address_space(1)))* gas_ptr;
typedef unsigned int __attribute__((address_space(3)))* las_ptr;

__global__ __launch_bounds__(512, 2) void gemm_log_kernel(
        const unsigned short* __restrict__ A,   // S x K bf16, row-major
        const unsigned short* __restrict__ B,   // N x K bf16, row-major
        const float* __restrict__ lz,
        float* __restrict__ out) {
    __shared__ __align__(16) char lds[NBUF * TILE_BYTES];   // 128 KB
    const int tid  = threadIdx.x;
    const int l    = tid & 63;
    const int w    = tid >> 6;         // 0..7: waves 0-3 consume, 4-7 produce
    const int bn = blockIdx.x & 7;     // XCD-affine: same-XCD blocks share the 1MB B-panel
    const int bm = blockIdx.x >> 3;    // 0..31

#define GLOAD(p_, o_) __builtin_amdgcn_global_load_lds((gas_ptr)(const void*)(p_), \
        (las_ptr)(void*)(lds + (o_)), 16, 0, 0)

    if (w >= 4) {
        // ================= PRODUCER waves =================
        const int pw = w - 4;                  // 0..3, stages slabs pw*4 .. pw*4+3
        const int kg = (l & 3) ^ ((l >> 3) & 3);   // pre-swizzled source chunk (rule #21)
        const unsigned short* src[4];
        int dst[4];
        #pragma unroll
        for (int i = 0; i < 4; ++i) {
            const int ri  = pw * 4 + i;            // 16-row slab 0..15
            const int row = ri * 16 + (l >> 2);    // local row 0..255
            src[i] = (ri < 8)
                ? A + (size_t)(bm * BM + row) * K_DIM + kg * 8
                : B + (size_t)(bn * BN + row - 128) * K_DIM + kg * 8;
            dst[i] = row * 64 + (l & 3) * 16;      // wave-uniform base + l*16
        }
#define STAGE(T, BUFI) { const int _ko = (T) * BK; const int _bo = (BUFI) * TILE_BYTES; \
        GLOAD(src[0] + _ko, _bo + dst[0]); GLOAD(src[1] + _ko, _bo + dst[1]);           \
        GLOAD(src[2] + _ko, _bo + dst[2]); GLOAD(src[3] + _ko, _bo + dst[3]); }
#define PBODY(T, BUFI, WAITN) {                                                         \
        asm volatile("s_waitcnt vmcnt(" #WAITN ")" ::: "memory");                       \
        __builtin_amdgcn_s_barrier();                                                   \
        STAGE((T) + 8, BUFI); }

        STAGE(0, 0); STAGE(1, 1); STAGE(2, 2); STAGE(3, 3);
        STAGE(4, 4); STAGE(5, 5); STAGE(6, 6); STAGE(7, 7);
        asm volatile("s_waitcnt vmcnt(28)" ::: "memory");   // tile 0 landed
        __builtin_amdgcn_s_barrier();                       // barrier #0
        for (int t8 = 0; t8 < NT - 8; t8 += 8) {            // T = 0..119
            PBODY(t8 + 0, 0, 24); PBODY(t8 + 1, 1, 24);
            PBODY(t8 + 2, 2, 24); PBODY(t8 + 3, 3, 24);
            PBODY(t8 + 4, 4, 24); PBODY(t8 + 5, 5, 24);
            PBODY(t8 + 6, 6, 24); PBODY(t8 + 7, 7, 24);
        }
        // drain: T = 120..126, no staging, counted vmcnt so consumers see each tile
        asm volatile("s_waitcnt vmcnt(24)" ::: "memory"); __builtin_amdgcn_s_barrier();
        asm volatile("s_waitcnt vmcnt(20)" ::: "memory"); __builtin_amdgcn_s_barrier();
        asm volatile("s_waitcnt vmcnt(16)" ::: "memory"); __builtin_amdgcn_s_barrier();
        asm volatile("s_waitcnt vmcnt(12)" ::: "memory"); __builtin_amdgcn_s_barrier();
        asm volatile("s_waitcnt vmcnt(8)"  ::: "memory"); __builtin_amdgcn_s_barrier();
        asm volatile("s_waitcnt vmcnt(4)"  ::: "memory"); __builtin_amdgcn_s_barrier();
        asm volatile("s_waitcnt vmcnt(0)"  ::: "memory"); __builtin_amdgcn_s_barrier();
        // total barriers: 1 + 120 + 7 = 128 (matches consumer)
#undef PBODY
#undef STAGE
    } else {
        // ================= CONSUMER waves =================
        const int wr = w >> 1, wc = w & 1;     // wave owns 64x64 quadrant
        const int lcol = l & 15, lk = l >> 4;
        const int swz = (lk ^ ((lcol >> 1) & 3)) << 4;
        int aoff[4], boff[4];
        #pragma unroll
        for (int m = 0; m < 4; ++m) aoff[m] = (wr * 64 + m * 16 + lcol) * 64 + swz;
        #pragma unroll
        for (int n = 0; n < 4; ++n) boff[n] = 8192 + (wc * 64 + n * 16 + lcol) * 64 + swz;

        f32x4 acc[4][4] = {};
        bf16x8 a0[4], b0[4], a1[4], b1[4];     // two statically-named frag sets (rule #20)

#define READF(RBUF, AR, BR) { const char* _rb = lds + (RBUF) * TILE_BYTES;              \
        _Pragma("unroll") for (int m = 0; m < 4; ++m)                                   \
            AR[m] = *reinterpret_cast<const bf16x8*>(_rb + aoff[m]);                    \
        _Pragma("unroll") for (int n = 0; n < 4; ++n)                                   \
            BR[n] = *reinterpret_cast<const bf16x8*>(_rb + boff[n]); }
#define MFMAS(AMM, BMM) {                                                               \
        __builtin_amdgcn_s_setprio(1);                                                  \
        _Pragma("unroll") for (int m = 0; m < 4; ++m)                                   \
            _Pragma("unroll") for (int n = 0; n < 4; ++n)                               \
                acc[m][n] = __builtin_amdgcn_mfma_f32_16x16x32_bf16(AMM[m], BMM[n],     \
                                                                    acc[m][n], 0, 0, 0);\
        __builtin_amdgcn_s_setprio(0); }
#define CBODY(T, RB, AR, BR, AMM, BMM) {                                                \
        __builtin_amdgcn_s_barrier();                                                   \
        READF(RB, AR, BR);                                                              \
        MFMAS(AMM, BMM); }

        __builtin_amdgcn_s_barrier();          // barrier #0: tile 0 landed
        READF(0, a0, b0);
        for (int t8 = 0; t8 < NT - 8; t8 += 8) {   // T = 0..119
            CBODY(t8 + 0, 1, a1, b1, a0, b0);
            CBODY(t8 + 1, 2, a0, b0, a1, b1);
            CBODY(t8 + 2, 3, a1, b1, a0, b0);
            CBODY(t8 + 3, 4, a0, b0, a1, b1);
            CBODY(t8 + 4, 5, a1, b1, a0, b0);
            CBODY(t8 + 5, 6, a0, b0, a1, b1);
            CBODY(t8 + 6, 7, a1, b1, a0, b0);
            CBODY(t8 + 7, 0, a0, b0, a1, b1);
        }
        CBODY(120, 1, a1, b1, a0, b0);         // T = 120..126
        CBODY(121, 2, a0, b0, a1, b1);
        CBODY(122, 3, a1, b1, a0, b0);
        CBODY(123, 4, a0, b0, a1, b1);
        CBODY(124, 5, a1, b1, a0, b0);
        CBODY(125, 6, a0, b0, a1, b1);
        CBODY(126, 7, a1, b1, a0, b0);
        MFMAS(a1, b1);                         // T = 127
#undef CBODY
#undef MFMAS
#undef READF

        // ---- epilogue: out = log(acc) - lz[col]; C/D: col=lane&15, row=(lane>>4)*4+j ----
        const int col_base = bn * BN + wc * 64;
        float lzv[4];
        #pragma unroll
        for (int n = 0; n < 4; ++n) lzv[n] = lz[col_base + n * 16 + lcol];
        #pragma unroll
        for (int m = 0; m < 4; ++m) {
            const int row0 = bm * BM + wr * 64 + m * 16 + lk * 4;
            #pragma unroll
            for (int n = 0; n < 4; ++n) {
                const int col = col_base + n * 16 + lcol;
                #pragma unroll
                for (int j = 0; j < 4; ++j)
                    out[(size_t)(row0 + j) * N_DIM + col] = __logf(acc[m][n][j]) - lzv[n];
            }
        }
    }
#undef GLOAD
}

// ---------------- emergency fallback (no workspace) ----------------
__global__ void naive_kernel(const float* __restrict__ ll1, const float* __restrict__ ll2,
                             const float* __restrict__ w1, const float* __restrict__ w2,
                             float* __restrict__ out) {
    int idx = blockIdx.x * blockDim.x + threadIdx.x;
    if (idx >= S_DIM * N_DIM) return;
    int s = idx >> 10, n = idx & (N_DIM - 1);
    const float* a1 = ll1 + (size_t)s * C_DIM;
    const float* a2 = ll2 + (size_t)s * C_DIM;
    const float* b1 = w1 + (size_t)n * C_DIM;
    const float* b2 = w2 + (size_t)n * C_DIM;
    float mx = -3.0e38f;
    for (int c = 0; c < C_DIM; ++c) mx = fmaxf(mx, b1[c]);
    for (int c = 0; c < C_DIM; ++c) mx = fmaxf(mx, b2[c]);
    float zs = 0.f, acc = 0.f;
    for (int c = 0; c < C_DIM; ++c) { zs += __expf(b1[c] - mx); acc += __expf(a1[c] + b1[c]); }
    for (int c = 0; c < C_DIM; ++c) { zs += __expf(b2[c] - mx); acc += __expf(a2[c] + b2[c]); }
    out[idx] = __logf(acc) - (mx + __logf(zs));
}

extern "C" void kernel_launch(void* const* d_in, const int* in_sizes, int n_in,
                              void* d_out, int out_size, void* d_ws, size_t ws_size,
                              hipStream_t stream) {
    const float* ll1 = (const float*)d_in[0];
    const float* ll2 = (const float*)d_in[1];
    const float* w1  = (const float*)d_in[2];
    const float* w2  = (const float*)d_in[3];
    float* out = (float*)d_out;

    const size_t a_elems = (size_t)S_DIM * K_DIM;
    const size_t b_elems = (size_t)N_DIM * K_DIM;
    const size_t need = (a_elems + b_elems) * sizeof(unsigned short) + N_DIM * sizeof(float);
    if (ws_size < need) {
        naive_kernel<<<(S_DIM * N_DIM + 255) / 256, 256, 0, stream>>>(ll1, ll2, w1, w2, out);
        return;
    }
    unsigned short* Aws = (unsigned short*)d_ws;
    unsigned short* Bws = Aws + a_elems;
    float* lzws = (float*)(Bws + b_elems);

    prepass_kernel<<<N_DIM + 2048, 256, 0, stream>>>(ll1, ll2, w1, w2, Aws, Bws, lzws);
    gemm_log_kernel<<<(S_DIM / BM) * (N_DIM / BN), 512, 0, stream>>>(Aws, Bws, lzws, out);
}